// Round 1
// baseline (526.871 us; speedup 1.0000x reference)
//
#include <hip/hip_runtime.h>
#include <hip/hip_bf16.h>
#include <math.h>

// ---------------------------------------------------------------------------
// CrossModalAttention on MI355X (gfx950)
//   B=4, Cu=320, Cj=1024, H=W=64 (N=4096), ATTN_DIM=256, scale = 1/16
//   out = unet + Wo @ (V @ softmax(Q^T K / 16)^T) + bo
// Strategy: bf16 MFMA everywhere, f32 accumulate. Flash-style attention.
// ---------------------------------------------------------------------------

typedef unsigned short u16;
typedef __attribute__((ext_vector_type(8))) short bf16x8;
typedef __attribute__((ext_vector_type(4))) float f32x4;
typedef __attribute__((ext_vector_type(4))) unsigned short u16x4;

#define NB 4
#define CU 320
#define CJ 1024
#define NN 4096
#define AD 256

// ws layout (bytes)
#define XU_OFF 0u                          // [B][N][320] bf16 = 10,485,760  (aliased by AO later)
#define XJ_OFF 10485760u                   // [B][N][1024] bf16 = 33,554,432
#define QB_OFF 44040192u                   // [B][N][256] bf16 = 8,388,608
#define KB_OFF 52428800u                   // [B][N][256] bf16 = 8,388,608
#define VB_OFF 60817408u                   // [B][320][N] bf16 = 10,485,760
#define WQ_OFF 71303168u                   // 256*320 bf16
#define WK_OFF 71467008u                   // 256*1024 bf16
#define WV_OFF 71991296u                   // 320*1024 bf16
#define WO_OFF 72646656u                   // 320*320 bf16
#define AO_OFF XU_OFF                      // [B][N][320] bf16 (aliases Xu, free after Q-proj)

__device__ __forceinline__ u16 f2b(float f) {
    union { float f; unsigned u; } v; v.f = f;
    unsigned u = v.u;
    unsigned r = (u + 0x7fffu + ((u >> 16) & 1u)) >> 16;
    return (u16)r;
}

// ---------------- weight cast ----------------
__global__ void wcast_kernel(const float* __restrict__ Wq, const float* __restrict__ Wk,
                             const float* __restrict__ Wv, const float* __restrict__ Wo,
                             u16* __restrict__ wq, u16* __restrict__ wk,
                             u16* __restrict__ wv, u16* __restrict__ wo) {
    int id = blockIdx.x * 256 + threadIdx.x;
    if (id < 81920) { wq[id] = f2b(Wq[id]); return; }
    id -= 81920;
    if (id < 262144) { wk[id] = f2b(Wk[id]); return; }
    id -= 262144;
    if (id < 327680) { wv[id] = f2b(Wv[id]); return; }
    id -= 327680;
    if (id < 102400) { wo[id] = f2b(Wo[id]); }
}

// ---------------- transpose [C][N] f32 -> [N][C] bf16 ----------------
__global__ __launch_bounds__(256) void transpose_cast_kernel(
        const float* __restrict__ in, u16* __restrict__ out, int C, int Nn) {
    __shared__ float tile[64][65];
    int b = blockIdx.z;
    int n0 = blockIdx.x * 64, c0 = blockIdx.y * 64;
    const float* src = in + (size_t)b * C * Nn;
    u16* dst = out + (size_t)b * Nn * C;
    int t = threadIdx.x;
    int nl = t & 63, cl = t >> 6;                 // cl: 0..3
    #pragma unroll
    for (int k = 0; k < 16; ++k) {
        int c = cl + k * 4;
        tile[c][nl] = src[(size_t)(c0 + c) * Nn + n0 + nl];
    }
    __syncthreads();
    int cl2 = t & 63, nl2 = t >> 6;
    #pragma unroll
    for (int k = 0; k < 16; ++k) {
        int n = nl2 + k * 4;
        dst[(size_t)(n0 + n) * C + c0 + cl2] = f2b(tile[cl2][n]);
    }
}

// ---------------- projection GEMM ----------------
// out[i][o] = (sum_c X[i][c]*W[o][c] + bias[o]) * alpha
// MODE 0: out layout [N][O] (row-major per batch)   (Q, K)
// MODE 1: out layout [O][N] (transposed store)      (V)
template <int MODE>
__global__ __launch_bounds__(256) void proj_gemm_kernel(
        const u16* __restrict__ X, const u16* __restrict__ W,
        const float* __restrict__ bias, u16* __restrict__ out,
        int C, int O, float alpha) {
    int b = blockIdx.z;
    const u16* Xb = X + (size_t)b * NN * C;
    u16* outb = out + (size_t)b * NN * O;
    int lane = threadIdx.x & 63, wave = threadIdx.x >> 6;
    int r = lane & 15, h = lane >> 4;
    int i0 = blockIdx.x * 64 + wave * 16;
    int o0 = blockIdx.y * 64;

    f32x4 acc[4];
    #pragma unroll
    for (int nt = 0; nt < 4; ++nt) acc[nt] = (f32x4)0.0f;

    const u16* arow = Xb + (size_t)(i0 + r) * C + h * 8;
    for (int kk = 0; kk < C; kk += 32) {
        bf16x8 a = *(const bf16x8*)(arow + kk);
        #pragma unroll
        for (int nt = 0; nt < 4; ++nt) {
            bf16x8 bb = *(const bf16x8*)(W + (size_t)(o0 + nt * 16 + r) * C + kk + h * 8);
            acc[nt] = __builtin_amdgcn_mfma_f32_16x16x32_bf16(a, bb, acc[nt], 0, 0, 0);
        }
    }
    #pragma unroll
    for (int nt = 0; nt < 4; ++nt) {
        int o = o0 + nt * 16 + r;
        float bs = bias[o];
        if (MODE == 0) {
            #pragma unroll
            for (int rr = 0; rr < 4; ++rr) {
                int i = i0 + h * 4 + rr;
                outb[(size_t)i * O + o] = f2b((acc[nt][rr] + bs) * alpha);
            }
        } else {
            u16x4 v;
            #pragma unroll
            for (int rr = 0; rr < 4; ++rr) v[rr] = f2b((acc[nt][rr] + bs) * alpha);
            *(u16x4*)(outb + (size_t)o * NN + i0 + h * 4) = v;
        }
    }
}

// ---------------- flash attention ----------------
// Q: [B][N][256] bf16 (pre-scaled by 1/16), K: [B][N][256], V: [B][320][N]
// AO: [B][N][320] bf16 = softmax(QK^T) V^T, normalized.
__global__ __launch_bounds__(256) void attn_kernel(
        const u16* __restrict__ Q, const u16* __restrict__ K,
        const u16* __restrict__ V, u16* __restrict__ AO) {
    const int KSTR = 264;   // padded row stride (elems) for K tile [32][256]
    const int VSTR = 40;    // padded row stride for V tile [320][32]
    __shared__ u16 K_lds[32 * KSTR];      // 16,896 B
    __shared__ u16 V_lds[320 * VSTR];     // 25,600 B
    __shared__ u16 P_lds[4 * 16 * 40];    //  5,120 B  (per-wave 16x32 P, pad 40)

    int b = blockIdx.y;
    int t = threadIdx.x;
    int lane = t & 63, wave = t >> 6;
    int r = lane & 15, h = lane >> 4;
    int i_base = blockIdx.x * 64 + wave * 16;

    const u16* Qb = Q + ((size_t)b * NN + i_base) * AD;
    const u16* Kb = K + (size_t)b * NN * AD;
    const u16* Vb = V + (size_t)b * CU * NN;
    u16* Pw = P_lds + wave * 16 * 40;

    // hoist Q fragments (16 rows x 256) into registers
    bf16x8 q[8];
    #pragma unroll
    for (int s = 0; s < 8; ++s)
        q[s] = *(const bf16x8*)(Qb + (size_t)r * AD + s * 32 + h * 8);

    f32x4 acc[20];
    #pragma unroll
    for (int nt = 0; nt < 20; ++nt) acc[nt] = (f32x4)0.0f;
    float m[4], lsum[4];
    #pragma unroll
    for (int rr = 0; rr < 4; ++rr) { m[rr] = -INFINITY; lsum[rr] = 0.0f; }

    for (int j0 = 0; j0 < NN; j0 += 32) {
        __syncthreads();   // protect prev-iter LDS reads
        // stage K tile: 32 rows x 256 = 1024 chunks of 16B
        #pragma unroll
        for (int cc = 0; cc < 4; ++cc) {
            int id = t + cc * 256;
            int row = id >> 5, c8 = id & 31;
            *(bf16x8*)(K_lds + row * KSTR + c8 * 8) =
                *(const bf16x8*)(Kb + (size_t)(j0 + row) * AD + c8 * 8);
        }
        // stage V tile: 320 rows x 32 = 1280 chunks of 16B
        #pragma unroll
        for (int cc = 0; cc < 5; ++cc) {
            int id = t + cc * 256;
            int row = id >> 2, c8 = id & 3;
            *(bf16x8*)(V_lds + row * VSTR + c8 * 8) =
                *(const bf16x8*)(Vb + (size_t)row * NN + j0 + c8 * 8);
        }
        __syncthreads();

        // S = Q K^T for 16 rows x 32 cols
        f32x4 s0 = (f32x4)0.0f, s1 = (f32x4)0.0f;
        #pragma unroll
        for (int s = 0; s < 8; ++s) {
            bf16x8 k0 = *(const bf16x8*)(K_lds + r * KSTR + s * 32 + h * 8);
            bf16x8 k1 = *(const bf16x8*)(K_lds + (16 + r) * KSTR + s * 32 + h * 8);
            s0 = __builtin_amdgcn_mfma_f32_16x16x32_bf16(q[s], k0, s0, 0, 0, 0);
            s1 = __builtin_amdgcn_mfma_f32_16x16x32_bf16(q[s], k1, s1, 0, 0, 0);
        }

        // online softmax; frag row = h*4+rr, col j0 + r (s0) / j0+16+r (s1)
        #pragma unroll
        for (int rr = 0; rr < 4; ++rr) {
            float tm = fmaxf(s0[rr], s1[rr]);
            tm = fmaxf(tm, __shfl_xor(tm, 1));
            tm = fmaxf(tm, __shfl_xor(tm, 2));
            tm = fmaxf(tm, __shfl_xor(tm, 4));
            tm = fmaxf(tm, __shfl_xor(tm, 8));
            float mn = fmaxf(m[rr], tm);
            float al = __expf(m[rr] - mn);
            m[rr] = mn;
            float p0 = __expf(s0[rr] - mn);
            float p1 = __expf(s1[rr] - mn);
            float ps = p0 + p1;
            ps += __shfl_xor(ps, 1);
            ps += __shfl_xor(ps, 2);
            ps += __shfl_xor(ps, 4);
            ps += __shfl_xor(ps, 8);
            lsum[rr] = lsum[rr] * al + ps;
            #pragma unroll
            for (int nt = 0; nt < 20; ++nt) acc[nt][rr] *= al;
            Pw[(h * 4 + rr) * 40 + r] = f2b(p0);
            Pw[(h * 4 + rr) * 40 + 16 + r] = f2b(p1);
        }
        asm volatile("s_waitcnt lgkmcnt(0)" ::: "memory");
        __builtin_amdgcn_sched_barrier(0);

        // PV: A = P (16x32), B = V tile (32 x 320)
        bf16x8 pa = *(const bf16x8*)(Pw + r * 40 + h * 8);
        #pragma unroll
        for (int nt = 0; nt < 20; ++nt) {
            bf16x8 vv = *(const bf16x8*)(V_lds + (nt * 16 + r) * VSTR + h * 8);
            acc[nt] = __builtin_amdgcn_mfma_f32_16x16x32_bf16(pa, vv, acc[nt], 0, 0, 0);
        }
    }

    // epilogue: normalize and store AO[b][i][c] bf16
    u16* AOb = AO + ((size_t)b * NN + i_base) * CU;
    #pragma unroll
    for (int rr = 0; rr < 4; ++rr) {
        float inv = 1.0f / lsum[rr];
        #pragma unroll
        for (int nt = 0; nt < 20; ++nt) {
            AOb[(size_t)(h * 4 + rr) * CU + nt * 16 + r] = f2b(acc[nt][rr] * inv);
        }
    }
}

// ---------------- final projection + residual ----------------
// out[b][o][i] = unet[b][o][i] + bo[o] + sum_c Wo[o][c] * AO[b][i][c]
__global__ __launch_bounds__(256) void final_gemm_kernel(
        const u16* __restrict__ AO, const u16* __restrict__ Wo,
        const float* __restrict__ bo, const float* __restrict__ unet,
        float* __restrict__ out) {
    int b = blockIdx.z;
    const u16* Ab = AO + (size_t)b * NN * CU;
    const float* ub = unet + (size_t)b * CU * NN;
    float* ob = out + (size_t)b * CU * NN;
    int lane = threadIdx.x & 63, wave = threadIdx.x >> 6;
    int r = lane & 15, h = lane >> 4;
    int i0 = blockIdx.x * 64 + wave * 16;
    int o0 = blockIdx.y * 64;

    f32x4 acc[4];
    #pragma unroll
    for (int nt = 0; nt < 4; ++nt) acc[nt] = (f32x4)0.0f;

    const u16* arow = Ab + (size_t)(i0 + r) * CU + h * 8;
    for (int kk = 0; kk < CU; kk += 32) {
        bf16x8 a = *(const bf16x8*)(arow + kk);
        #pragma unroll
        for (int nt = 0; nt < 4; ++nt) {
            bf16x8 w = *(const bf16x8*)(Wo + (size_t)(o0 + nt * 16 + r) * CU + kk + h * 8);
            acc[nt] = __builtin_amdgcn_mfma_f32_16x16x32_bf16(a, w, acc[nt], 0, 0, 0);
        }
    }
    #pragma unroll
    for (int nt = 0; nt < 4; ++nt) {
        int o = o0 + nt * 16 + r;
        float bb = bo[o];
        size_t base = (size_t)o * NN + i0 + h * 4;
        f32x4 res;
        f32x4 u = *(const f32x4*)(ub + base);
        #pragma unroll
        for (int rr = 0; rr < 4; ++rr) res[rr] = acc[nt][rr] + bb + u[rr];
        *(f32x4*)(ob + base) = res;
    }
}

extern "C" void kernel_launch(void* const* d_in, const int* in_sizes, int n_in,
                              void* d_out, int out_size, void* d_ws, size_t ws_size,
                              hipStream_t stream) {
    const float* unet  = (const float*)d_in[0];
    const float* janus = (const float*)d_in[1];
    const float* Wq = (const float*)d_in[2];
    const float* bq = (const float*)d_in[3];
    const float* Wk = (const float*)d_in[4];
    const float* bk = (const float*)d_in[5];
    const float* Wv = (const float*)d_in[6];
    const float* bv = (const float*)d_in[7];
    const float* Wo = (const float*)d_in[8];
    const float* bo = (const float*)d_in[9];
    float* out = (float*)d_out;

    char* ws = (char*)d_ws;
    u16* Xu  = (u16*)(ws + XU_OFF);
    u16* Xj  = (u16*)(ws + XJ_OFF);
    u16* Qb  = (u16*)(ws + QB_OFF);
    u16* Kb  = (u16*)(ws + KB_OFF);
    u16* Vb  = (u16*)(ws + VB_OFF);
    u16* wq  = (u16*)(ws + WQ_OFF);
    u16* wk  = (u16*)(ws + WK_OFF);
    u16* wv  = (u16*)(ws + WV_OFF);
    u16* wo  = (u16*)(ws + WO_OFF);
    u16* AO  = (u16*)(ws + AO_OFF);   // aliases Xu (free after Q projection)

    // 1. cast weights to bf16
    wcast_kernel<<<3024, 256, 0, stream>>>(Wq, Wk, Wv, Wo, wq, wk, wv, wo);

    // 2. transpose inputs to [B][N][C] bf16
    transpose_cast_kernel<<<dim3(64, 5, NB), 256, 0, stream>>>(unet, Xu, CU, NN);
    transpose_cast_kernel<<<dim3(64, 16, NB), 256, 0, stream>>>(janus, Xj, CJ, NN);

    // 3. projections (Q pre-scaled by 1/16)
    proj_gemm_kernel<0><<<dim3(64, 4, NB), 256, 0, stream>>>(Xu, wq, bq, Qb, CU, AD, 0.0625f);
    proj_gemm_kernel<0><<<dim3(64, 4, NB), 256, 0, stream>>>(Xj, wk, bk, Kb, CJ, AD, 1.0f);
    proj_gemm_kernel<1><<<dim3(64, 5, NB), 256, 0, stream>>>(Xj, wv, bv, Vb, CJ, CU, 1.0f);

    // 4. flash attention
    attn_kernel<<<dim3(64, NB), 256, 0, stream>>>(Qb, Kb, Vb, AO);

    // 5. output projection + bias + residual
    final_gemm_kernel<<<dim3(64, 5, NB), 256, 0, stream>>>(AO, wo, bo, unet, out);
}